// Round 1
// baseline (1097.655 us; speedup 1.0000x reference)
//
#include <hip/hip_runtime.h>
#include <stdint.h>

#define BB 4
#define SS 2048
#define DD 512
#define HH 8
#define DKK 64
#define MR (BB*SS)   // 8192 rows

// ---------------------------------------------------------------------------
// GEMM: C[M,N] = A[M,K] @ W[N,K]^T (+ bias), torch Linear convention.
// 128x128 tile, BK=16, 256 threads, 8x8 per thread. fp32 vector FMA.
// ---------------------------------------------------------------------------
template<bool HAS_BIAS>
__global__ __launch_bounds__(256)
void gemm_nt_f32(const float* __restrict__ A, const float* __restrict__ W,
                 const float* __restrict__ bias, float* __restrict__ C,
                 int M, int N, int K)
{
    __shared__ float As[16][132];   // [k][row], padded
    __shared__ float Ws[16][132];   // [k][col], padded
    const int tid = threadIdx.x;
    const int tx  = tid & 15;
    const int ty  = tid >> 4;
    const int row0 = blockIdx.y * 128;
    const int col0 = blockIdx.x * 128;

    float acc[8][8];
#pragma unroll
    for (int i = 0; i < 8; ++i)
#pragma unroll
        for (int j = 0; j < 8; ++j) acc[i][j] = 0.0f;

    const int rA = tid >> 2;   // 0..63
    const int kq = tid & 3;    // 0..3 -> float4 within the 16-wide k slice

    for (int k0 = 0; k0 < K; k0 += 16) {
#pragma unroll
        for (int half = 0; half < 2; ++half) {
            const int r = rA + half * 64;
            const float4 av = *(const float4*)&A[(size_t)(row0 + r) * K + k0 + kq * 4];
            const float4 wv = *(const float4*)&W[(size_t)(col0 + r) * K + k0 + kq * 4];
            As[kq*4+0][r] = av.x; As[kq*4+1][r] = av.y;
            As[kq*4+2][r] = av.z; As[kq*4+3][r] = av.w;
            Ws[kq*4+0][r] = wv.x; Ws[kq*4+1][r] = wv.y;
            Ws[kq*4+2][r] = wv.z; Ws[kq*4+3][r] = wv.w;
        }
        __syncthreads();
#pragma unroll
        for (int kk = 0; kk < 16; ++kk) {
            const float4 a0 = *(const float4*)&As[kk][ty*8];
            const float4 a1 = *(const float4*)&As[kk][ty*8+4];
            const float4 b0 = *(const float4*)&Ws[kk][tx*8];
            const float4 b1 = *(const float4*)&Ws[kk][tx*8+4];
            const float a[8] = {a0.x,a0.y,a0.z,a0.w,a1.x,a1.y,a1.z,a1.w};
            const float b[8] = {b0.x,b0.y,b0.z,b0.w,b1.x,b1.y,b1.z,b1.w};
#pragma unroll
            for (int i = 0; i < 8; ++i)
#pragma unroll
                for (int j = 0; j < 8; ++j)
                    acc[i][j] = fmaf(a[i], b[j], acc[i][j]);
        }
        __syncthreads();
    }

#pragma unroll
    for (int i = 0; i < 8; ++i) {
        const int row = row0 + ty * 8 + i;
#pragma unroll
        for (int jq = 0; jq < 2; ++jq) {
            const int col = col0 + tx * 8 + jq * 4;
            float4 o;
            o.x = acc[i][jq*4+0];
            o.y = acc[i][jq*4+1];
            o.z = acc[i][jq*4+2];
            o.w = acc[i][jq*4+3];
            if (HAS_BIAS) {
                o.x += bias[col+0]; o.y += bias[col+1];
                o.z += bias[col+2]; o.w += bias[col+3];
            }
            *(float4*)&C[(size_t)row * N + col] = o;
        }
    }
}

// ---------------------------------------------------------------------------
// Flash attention, fp32. One block = one (b, h, 64-row q-tile).
// 256 threads as 16x16; each thread owns a 4x4 score block and 4x4 of O.
// Online softmax with 16-lane shuffle reductions. LDS = 64 KB exactly.
// ---------------------------------------------------------------------------
__global__ __launch_bounds__(256)
void flash_attn_f32(const float* __restrict__ Qp, const float* __restrict__ Kp,
                    const float* __restrict__ Vp, const uint8_t* __restrict__ mask,
                    float* __restrict__ Op)
{
    __shared__ float Qs[64][64];  // [dk][qrow]   (transposed)
    __shared__ float Ks[64][64];  // [dk][krow]   (transposed)
    __shared__ float Vs[64][64];  // [krow][dk]   xor-swizzled cols
    __shared__ float Ps[64][64];  // [krow][qrow] xor-swizzled cols

    const int tid = threadIdx.x;
    const int tx = tid & 15;
    const int ty = tid >> 4;
    const int r0 = ty * 4;   // local q rows
    const int c0 = tx * 4;   // local key cols (QK phase) / dk cols (PV phase)
    const int q0 = blockIdx.x * 64;
    const int h  = blockIdx.y;
    const int b  = blockIdx.z;

    const int lr  = tid >> 2;       // load row 0..63
    const int lc4 = (tid & 3) * 4;  // base float4-col

    {   // Q tile -> Qs[dk][row]
        const size_t base = ((size_t)b * SS + q0) * DD + h * DKK;
#pragma unroll
        for (int i = 0; i < 4; ++i) {
            const int c4 = lc4 + i;
            const float4 v = *(const float4*)&Qp[base + (size_t)lr * DD + c4 * 4];
            Qs[c4*4+0][lr] = v.x; Qs[c4*4+1][lr] = v.y;
            Qs[c4*4+2][lr] = v.z; Qs[c4*4+3][lr] = v.w;
        }
    }

    float m[4], l[4], O[4][4];
#pragma unroll
    for (int i = 0; i < 4; ++i) {
        m[i] = -1e30f; l[i] = 0.0f;
#pragma unroll
        for (int j = 0; j < 4; ++j) O[i][j] = 0.0f;
    }

    for (int k0 = 0; k0 < SS; k0 += 64) {
        {   // K tile -> Ks[dk][row]; V tile -> Vs[row][dk] (swizzled)
            const size_t base = ((size_t)b * SS + k0) * DD + h * DKK;
#pragma unroll
            for (int i = 0; i < 4; ++i) {
                const int c4 = lc4 + i;
                const float4 kv = *(const float4*)&Kp[base + (size_t)lr * DD + c4 * 4];
                Ks[c4*4+0][lr] = kv.x; Ks[c4*4+1][lr] = kv.y;
                Ks[c4*4+2][lr] = kv.z; Ks[c4*4+3][lr] = kv.w;
                const float4 vv = *(const float4*)&Vp[base + (size_t)lr * DD + c4 * 4];
                *(float4*)&Vs[lr][(c4 * 4) ^ ((lr & 3) << 4)] = vv;
            }
        }
        __syncthreads();

        // padding-mask addend for this thread's 4 key columns
        const uchar4 mk = *(const uchar4*)&mask[(size_t)b * SS + k0 + c0];
        float madd[4];
        madd[0] = mk.x ? -INFINITY : 0.0f;
        madd[1] = mk.y ? -INFINITY : 0.0f;
        madd[2] = mk.z ? -INFINITY : 0.0f;
        madd[3] = mk.w ? -INFINITY : 0.0f;

        float s[4][4];
#pragma unroll
        for (int i = 0; i < 4; ++i)
#pragma unroll
            for (int j = 0; j < 4; ++j) s[i][j] = 0.0f;

#pragma unroll
        for (int kk = 0; kk < 64; ++kk) {
            const float4 q = *(const float4*)&Qs[kk][r0];
            const float4 k = *(const float4*)&Ks[kk][c0];
            const float qa[4] = {q.x,q.y,q.z,q.w};
            const float kb[4] = {k.x,k.y,k.z,k.w};
#pragma unroll
            for (int i = 0; i < 4; ++i)
#pragma unroll
                for (int j = 0; j < 4; ++j)
                    s[i][j] = fmaf(qa[i], kb[j], s[i][j]);
        }

        float fac[4];
#pragma unroll
        for (int i = 0; i < 4; ++i) {
#pragma unroll
            for (int j = 0; j < 4; ++j)
                s[i][j] = s[i][j] * 0.125f + madd[j];   // 1/sqrt(64)=0.125
            float tm = fmaxf(fmaxf(s[i][0], s[i][1]), fmaxf(s[i][2], s[i][3]));
#pragma unroll
            for (int off = 8; off >= 1; off >>= 1)
                tm = fmaxf(tm, __shfl_xor(tm, off, 16));
            float mn = fmaxf(m[i], tm);
            mn = fmaxf(mn, -1e30f);                     // all-masked guard
            fac[i] = __expf(m[i] - mn);
            float ls = 0.0f;
#pragma unroll
            for (int j = 0; j < 4; ++j) {
                const float p = __expf(s[i][j] - mn);   // -inf -> 0
                s[i][j] = p;
                ls += p;
            }
#pragma unroll
            for (int off = 8; off >= 1; off >>= 1)
                ls += __shfl_xor(ls, off, 16);
            l[i] = l[i] * fac[i] + ls;
            m[i] = mn;
        }

        // P -> LDS transposed [key][qrow], xor-swizzled to spread banks
#pragma unroll
        for (int j = 0; j < 4; ++j) {
            const int c = c0 + j;
            float4 pv;
            pv.x = s[0][j]; pv.y = s[1][j]; pv.z = s[2][j]; pv.w = s[3][j];
            *(float4*)&Ps[c][r0 ^ ((c & 15) << 2)] = pv;
        }
        __syncthreads();

#pragma unroll
        for (int i = 0; i < 4; ++i)
#pragma unroll
            for (int j = 0; j < 4; ++j) O[i][j] *= fac[i];

#pragma unroll
        for (int kk = 0; kk < 64; ++kk) {
            const float4 p = *(const float4*)&Ps[kk][r0 ^ ((kk & 15) << 2)];
            const float4 v = *(const float4*)&Vs[kk][c0 ^ ((kk & 3) << 4)];
            const float pa[4] = {p.x,p.y,p.z,p.w};
            const float vb[4] = {v.x,v.y,v.z,v.w};
#pragma unroll
            for (int i = 0; i < 4; ++i)
#pragma unroll
                for (int j = 0; j < 4; ++j)
                    O[i][j] = fmaf(pa[i], vb[j], O[i][j]);
        }
        __syncthreads();
    }

    // write attention output in [b, s, h, dk] layout (== [b,s,D] flat)
#pragma unroll
    for (int i = 0; i < 4; ++i) {
        const float inv = (l[i] > 0.0f) ? (1.0f / l[i]) : 0.0f;  // masked row -> 0
        float4 o;
        o.x = O[i][0]*inv; o.y = O[i][1]*inv; o.z = O[i][2]*inv; o.w = O[i][3]*inv;
        *(float4*)&Op[(((size_t)b * SS + q0 + r0 + i) * DD) + h * DKK + c0] = o;
    }
}

// ---------------------------------------------------------------------------
extern "C" void kernel_launch(void* const* d_in, const int* in_sizes, int n_in,
                              void* d_out, int out_size, void* d_ws, size_t ws_size,
                              hipStream_t stream)
{
    const float*   query = (const float*)d_in[0];
    const float*   key   = (const float*)d_in[1];
    const float*   value = (const float*)d_in[2];
    const uint8_t* mask  = (const uint8_t*)d_in[3];
    const float*   Wq    = (const float*)d_in[4];
    const float*   Wk    = (const float*)d_in[5];
    const float*   Wv    = (const float*)d_in[6];
    const float*   Wo    = (const float*)d_in[7];
    const float*   bo    = (const float*)d_in[8];
    float*         out   = (float*)d_out;

    float* ws = (float*)d_ws;
    const size_t mat = (size_t)MR * DD;      // 8192*512 floats = 16.8 MB
    float* Qp = ws;
    float* Kp = ws + mat;
    float* Vp = ws + 2 * mat;
    float* Ap = ws + 3 * mat;

    dim3 gGemm(DD / 128, MR / 128);          // (4, 64)
    gemm_nt_f32<false><<<gGemm, 256, 0, stream>>>(query, Wq, nullptr, Qp, MR, DD, DD);
    gemm_nt_f32<false><<<gGemm, 256, 0, stream>>>(key,   Wk, nullptr, Kp, MR, DD, DD);
    gemm_nt_f32<false><<<gGemm, 256, 0, stream>>>(value, Wv, nullptr, Vp, MR, DD, DD);

    dim3 gAttn(SS / 64, HH, BB);             // (32, 8, 4)
    flash_attn_f32<<<gAttn, 256, 0, stream>>>(Qp, Kp, Vp, mask, Ap);

    gemm_nt_f32<true><<<gGemm, 256, 0, stream>>>(Ap, Wo, bo, out, MR, DD, DD);
}

// Round 4
// 491.064 us; speedup vs baseline: 2.2353x; 2.2353x over previous
//
#include <hip/hip_runtime.h>
#include <stdint.h>

#define BB 4
#define SS 2048
#define DD 512
#define HH 8
#define DKK 64
#define MR (BB*SS)   // 8192 rows

typedef __attribute__((ext_vector_type(8))) short short8v;
typedef __attribute__((ext_vector_type(4))) short short4v;
typedef __attribute__((ext_vector_type(4))) float f32x4;

static __device__ __forceinline__ short f2bf(float x) {
    uint32_t u = __float_as_uint(x);
    u += 0x7fffu + ((u >> 16) & 1u);   // round to nearest even
    return (short)(u >> 16);
}

// ---------------------------------------------------------------------------
// GEMM: C[M,N] = A[M,K] @ W[N,K]^T (+ bias). fp32 vector FMA (unchanged).
// ---------------------------------------------------------------------------
template<bool HAS_BIAS>
__global__ __launch_bounds__(256)
void gemm_nt_f32(const float* __restrict__ A, const float* __restrict__ W,
                 const float* __restrict__ bias, float* __restrict__ C,
                 int M, int N, int K)
{
    __shared__ float As[16][132];
    __shared__ float Ws[16][132];
    const int tid = threadIdx.x;
    const int tx  = tid & 15;
    const int ty  = tid >> 4;
    const int row0 = blockIdx.y * 128;
    const int col0 = blockIdx.x * 128;

    float acc[8][8];
#pragma unroll
    for (int i = 0; i < 8; ++i)
#pragma unroll
        for (int j = 0; j < 8; ++j) acc[i][j] = 0.0f;

    const int rA = tid >> 2;
    const int kq = tid & 3;

    for (int k0 = 0; k0 < K; k0 += 16) {
#pragma unroll
        for (int half = 0; half < 2; ++half) {
            const int r = rA + half * 64;
            const float4 av = *(const float4*)&A[(size_t)(row0 + r) * K + k0 + kq * 4];
            const float4 wv = *(const float4*)&W[(size_t)(col0 + r) * K + k0 + kq * 4];
            As[kq*4+0][r] = av.x; As[kq*4+1][r] = av.y;
            As[kq*4+2][r] = av.z; As[kq*4+3][r] = av.w;
            Ws[kq*4+0][r] = wv.x; Ws[kq*4+1][r] = wv.y;
            Ws[kq*4+2][r] = wv.z; Ws[kq*4+3][r] = wv.w;
        }
        __syncthreads();
#pragma unroll
        for (int kk = 0; kk < 16; ++kk) {
            const float4 a0 = *(const float4*)&As[kk][ty*8];
            const float4 a1 = *(const float4*)&As[kk][ty*8+4];
            const float4 b0 = *(const float4*)&Ws[kk][tx*8];
            const float4 b1 = *(const float4*)&Ws[kk][tx*8+4];
            const float a[8] = {a0.x,a0.y,a0.z,a0.w,a1.x,a1.y,a1.z,a1.w};
            const float b[8] = {b0.x,b0.y,b0.z,b0.w,b1.x,b1.y,b1.z,b1.w};
#pragma unroll
            for (int i = 0; i < 8; ++i)
#pragma unroll
                for (int j = 0; j < 8; ++j)
                    acc[i][j] = fmaf(a[i], b[j], acc[i][j]);
        }
        __syncthreads();
    }

#pragma unroll
    for (int i = 0; i < 8; ++i) {
        const int row = row0 + ty * 8 + i;
#pragma unroll
        for (int jq = 0; jq < 2; ++jq) {
            const int col = col0 + tx * 8 + jq * 4;
            float4 o;
            o.x = acc[i][jq*4+0];
            o.y = acc[i][jq*4+1];
            o.z = acc[i][jq*4+2];
            o.w = acc[i][jq*4+3];
            if (HAS_BIAS) {
                o.x += bias[col+0]; o.y += bias[col+1];
                o.z += bias[col+2]; o.w += bias[col+3];
            }
            *(float4*)&C[(size_t)row * N + col] = o;
        }
    }
}

// ---------------------------------------------------------------------------
// Flash attention with bf16 MFMA (fp32 accum).
// Block = 4 waves = 256 thr. Q-tile 128 (32 rows/wave, 2x16 stripes), KV 64.
// mfma_f32_16x16x32_bf16: A lane: row=l&15, k=(l>>4)*8+[0..7]; B lane:
// col=l&15, same k; C/D: col=l&15, row=(l>>4)*4+reg  [m89/m91 verified].
// LDS: K[64][64] bf16, Vt[64][64] bf16 (V transposed), P per-wave [32][64].
// All with 16B-granule XOR swizzle: gran ^= (row&7)  (m214 recipe).
// ---------------------------------------------------------------------------
__global__ __launch_bounds__(256, 2)
void flash_attn_mfma(const float* __restrict__ Qp, const float* __restrict__ Kp,
                     const float* __restrict__ Vp, const uint8_t* __restrict__ mask,
                     float* __restrict__ Op)
{
    __shared__ short KsL[64*64];     // 8 KB
    __shared__ short VtL[64*64];     // 8 KB
    __shared__ short PsL[4][32*64];  // 16 KB

    const int tid  = threadIdx.x;
    const int w    = tid >> 6;
    const int lane = tid & 63;
    const int lr   = lane & 15;
    const int lg   = lane >> 4;
    const int q0   = blockIdx.x * 128;
    const int h    = blockIdx.y;
    const int b    = blockIdx.z;
    const size_t bS = (size_t)b * SS;

    // ---- Q fragments, pre-scaled by 1/sqrt(DK) ----
    short8v qf[2][2];
#pragma unroll
    for (int s2 = 0; s2 < 2; ++s2)
#pragma unroll
    for (int ds = 0; ds < 2; ++ds) {
        const float* p = &Qp[(bS + q0 + w*32 + s2*16 + lr) * DD + h*DKK + ds*32 + lg*8];
        const float4 a = *(const float4*)p;
        const float4 c = *(const float4*)(p + 4);
        short8v v;
        v[0]=f2bf(a.x*0.125f); v[1]=f2bf(a.y*0.125f); v[2]=f2bf(a.z*0.125f); v[3]=f2bf(a.w*0.125f);
        v[4]=f2bf(c.x*0.125f); v[5]=f2bf(c.y*0.125f); v[6]=f2bf(c.z*0.125f); v[7]=f2bf(c.w*0.125f);
        qf[s2][ds] = v;
    }

    float m_[2][4], l_[2][4];
    f32x4 Oc[2][4];
#pragma unroll
    for (int s2 = 0; s2 < 2; ++s2) {
#pragma unroll
        for (int r = 0; r < 4; ++r) { m_[s2][r] = -1e30f; l_[s2][r] = 0.0f; }
#pragma unroll
        for (int dt = 0; dt < 4; ++dt) Oc[s2][dt] = (f32x4)0.0f;
    }

    // staging geometry
    const int krow_b = tid >> 4;        // K: row = j*16 + krow_b
    const int kf4    = tid & 15;        //    float4-chunk within row
    const int vr0    = (tid & 15) * 4;  // V: 4 rows vr0..vr0+3
    const int vc0    = (tid >> 4) * 4;  //    4 d-cols vc0..vc0+3

    float kvf[4][4], vvf[4][4];
#pragma unroll
    for (int j = 0; j < 4; ++j) {
        *(float4*)kvf[j] = *(const float4*)&Kp[(bS + (j*16 + krow_b)) * DD + h*DKK + kf4*4];
        *(float4*)vvf[j] = *(const float4*)&Vp[(bS + (vr0 + j)) * DD + h*DKK + vc0];
    }

    for (int it = 0; it < SS/64; ++it) {
        const int k0 = it * 64;
        __syncthreads();   // prior iteration's K/Vt reads complete

        // ---- stage K (row-major) and V (transposed) into LDS, swizzled ----
#pragma unroll
        for (int j = 0; j < 4; ++j) {
            const int row = j*16 + krow_b;
            short4v kv;
            kv[0]=f2bf(kvf[j][0]); kv[1]=f2bf(kvf[j][1]);
            kv[2]=f2bf(kvf[j][2]); kv[3]=f2bf(kvf[j][3]);
            *(short4v*)&KsL[row*64 + (((kf4>>1) ^ (row&7))*8 + (kf4&1)*4)] = kv;
        }
#pragma unroll
        for (int j2 = 0; j2 < 4; ++j2) {
            const int d = vc0 + j2;
            short4v tv;
            tv[0]=f2bf(vvf[0][j2]); tv[1]=f2bf(vvf[1][j2]);
            tv[2]=f2bf(vvf[2][j2]); tv[3]=f2bf(vvf[3][j2]);
            *(short4v*)&VtL[d*64 + (((vr0>>3) ^ (d&7))*8 + (vr0&7))] = tv;
        }
        __syncthreads();   // staging visible

        // ---- prefetch next tile (overlaps with compute below) ----
        if (it + 1 < SS/64) {
            const int kn = k0 + 64;
#pragma unroll
            for (int j = 0; j < 4; ++j) {
                *(float4*)kvf[j] = *(const float4*)&Kp[(bS + kn + (j*16 + krow_b)) * DD + h*DKK + kf4*4];
                *(float4*)vvf[j] = *(const float4*)&Vp[(bS + kn + (vr0 + j)) * DD + h*DKK + vc0];
            }
        }

        // ---- mask addends for this lane's 4 key columns ----
        float madd[4];
#pragma unroll
        for (int t = 0; t < 4; ++t)
            madd[t] = mask[bS + k0 + t*16 + lr] ? -INFINITY : 0.0f;

        // ---- K B-fragments ----
        short8v kfb[4][2];
#pragma unroll
        for (int t = 0; t < 4; ++t)
#pragma unroll
        for (int ds = 0; ds < 2; ++ds) {
            const int row = t*16 + lr;
            kfb[t][ds] = *(const short8v*)&KsL[row*64 + (((ds*4 + lg) ^ (row&7)) * 8)];
        }

        // ---- QK^T + online softmax, per 16-row stripe ----
        float fac[2][4];
#pragma unroll
        for (int s2 = 0; s2 < 2; ++s2) {
            f32x4 sc[4];
#pragma unroll
            for (int t = 0; t < 4; ++t) {
                sc[t] = (f32x4)0.0f;
                sc[t] = __builtin_amdgcn_mfma_f32_16x16x32_bf16(qf[s2][0], kfb[t][0], sc[t], 0, 0, 0);
                sc[t] = __builtin_amdgcn_mfma_f32_16x16x32_bf16(qf[s2][1], kfb[t][1], sc[t], 0, 0, 0);
            }
            float ss[4][4];
#pragma unroll
            for (int t = 0; t < 4; ++t)
#pragma unroll
            for (int r = 0; r < 4; ++r) ss[t][r] = sc[t][r] + madd[t];

#pragma unroll
            for (int r = 0; r < 4; ++r) {
                float tm = fmaxf(fmaxf(ss[0][r], ss[1][r]), fmaxf(ss[2][r], ss[3][r]));
#pragma unroll
                for (int off = 1; off <= 8; off <<= 1) tm = fmaxf(tm, __shfl_xor(tm, off));
                const float mn = fmaxf(m_[s2][r], tm);
                const float fc = __expf(m_[s2][r] - mn);
                m_[s2][r] = mn;
                float lsum = 0.0f;
#pragma unroll
                for (int t = 0; t < 4; ++t) {
                    const float p = __expf(ss[t][r] - mn);
                    ss[t][r] = p;
                    lsum += p;
                }
#pragma unroll
                for (int off = 1; off <= 8; off <<= 1) lsum += __shfl_xor(lsum, off);
                l_[s2][r] = l_[s2][r] * fc + lsum;
                fac[s2][r] = fc;
            }

            // ---- P -> per-wave LDS (bf16), same granule swizzle ----
#pragma unroll
            for (int t = 0; t < 4; ++t)
#pragma unroll
            for (int r = 0; r < 4; ++r) {
                const int qrow = s2*16 + lg*4 + r;
                const int k = t*16 + lr;
                PsL[w][qrow*64 + (((k>>3) ^ (qrow&7))*8 + (k&7))] = f2bf(ss[t][r]);
            }
        }

        // ---- rescale O ----
#pragma unroll
        for (int s2 = 0; s2 < 2; ++s2)
#pragma unroll
        for (int dt = 0; dt < 4; ++dt)
#pragma unroll
        for (int r = 0; r < 4; ++r) Oc[s2][dt][r] *= fac[s2][r];

        // ---- PV: O += P @ V ----
        short8v pf[2][2];
#pragma unroll
        for (int s2 = 0; s2 < 2; ++s2)
#pragma unroll
        for (int ks = 0; ks < 2; ++ks) {
            const int row = s2*16 + lr;
            pf[s2][ks] = *(const short8v*)&PsL[w][row*64 + (((ks*4 + lg) ^ (row&7)) * 8)];
        }
        short8v vfb[4][2];
#pragma unroll
        for (int dt = 0; dt < 4; ++dt)
#pragma unroll
        for (int ks = 0; ks < 2; ++ks) {
            const int d = dt*16 + lr;
            vfb[dt][ks] = *(const short8v*)&VtL[d*64 + (((ks*4 + lg) ^ (d&7)) * 8)];
        }
#pragma unroll
        for (int s2 = 0; s2 < 2; ++s2)
#pragma unroll
        for (int dt = 0; dt < 4; ++dt) {
            Oc[s2][dt] = __builtin_amdgcn_mfma_f32_16x16x32_bf16(pf[s2][0], vfb[dt][0], Oc[s2][dt], 0, 0, 0);
            Oc[s2][dt] = __builtin_amdgcn_mfma_f32_16x16x32_bf16(pf[s2][1], vfb[dt][1], Oc[s2][dt], 0, 0, 0);
        }
    }

    // ---- epilogue: normalize and store [b,s,h,dk] ----
#pragma unroll
    for (int s2 = 0; s2 < 2; ++s2)
#pragma unroll
    for (int r = 0; r < 4; ++r) {
        const float inv = (l_[s2][r] > 0.0f) ? (1.0f / l_[s2][r]) : 0.0f;
        const int q = q0 + w*32 + s2*16 + lg*4 + r;
#pragma unroll
        for (int dt = 0; dt < 4; ++dt)
            Op[(bS + q) * DD + h*DKK + dt*16 + lr] = Oc[s2][dt][r] * inv;
    }
}

// ---------------------------------------------------------------------------
extern "C" void kernel_launch(void* const* d_in, const int* in_sizes, int n_in,
                              void* d_out, int out_size, void* d_ws, size_t ws_size,
                              hipStream_t stream)
{
    const float*   query = (const float*)d_in[0];
    const float*   key   = (const float*)d_in[1];
    const float*   value = (const float*)d_in[2];
    const uint8_t* mask  = (const uint8_t*)d_in[3];
    const float*   Wq    = (const float*)d_in[4];
    const float*   Wk    = (const float*)d_in[5];
    const float*   Wv    = (const float*)d_in[6];
    const float*   Wo    = (const float*)d_in[7];
    const float*   bo    = (const float*)d_in[8];
    float*         out   = (float*)d_out;

    float* ws = (float*)d_ws;
    const size_t mat = (size_t)MR * DD;
    float* Qp = ws;
    float* Kp = ws + mat;
    float* Vp = ws + 2 * mat;
    float* Ap = ws + 3 * mat;

    dim3 gGemm(DD / 128, MR / 128);
    gemm_nt_f32<false><<<gGemm, 256, 0, stream>>>(query, Wq, nullptr, Qp, MR, DD, DD);
    gemm_nt_f32<false><<<gGemm, 256, 0, stream>>>(key,   Wk, nullptr, Kp, MR, DD, DD);
    gemm_nt_f32<false><<<gGemm, 256, 0, stream>>>(value, Wv, nullptr, Vp, MR, DD, DD);

    dim3 gAttn(SS / 128, HH, BB);
    flash_attn_mfma<<<gAttn, 256, 0, stream>>>(Qp, Kp, Vp, mask, Ap);

    gemm_nt_f32<true><<<gGemm, 256, 0, stream>>>(Ap, Wo, bo, out, MR, DD, DD);
}

// Round 8
// 256.095 us; speedup vs baseline: 4.2861x; 1.9175x over previous
//
#include <hip/hip_runtime.h>
#include <stdint.h>

#define BB 4
#define SS 2048
#define DD 512
#define HH 8
#define DKK 64
#define MR (BB*SS)              // 8192 rows
#define NE (MR*DD)              // 4194304 elements per activation matrix
#define NW (DD*DD)              // 262144 per weight

using half8v = __attribute__((ext_vector_type(8))) _Float16;
using half4v = __attribute__((ext_vector_type(4))) _Float16;
using f32x4  = __attribute__((ext_vector_type(4))) float;

__device__ __forceinline__ void gload_lds16(const void* g, void* l) {
    __builtin_amdgcn_global_load_lds((const __attribute__((address_space(1))) void*)g,
                                     (__attribute__((address_space(3))) void*)l, 16, 0, 0);
}

// ---------------------------------------------------------------------------
// Convert 7 fp32 tensors -> fp16. Block = 2048 elems. Sizes are compile-time:
// q,k,v: 2048 blocks each; Wq,Wk,Wv,Wo: 128 blocks each. Total 6656 blocks.
// ---------------------------------------------------------------------------
struct CvtArgs { const float* s[7]; _Float16* d[7]; };

__global__ __launch_bounds__(256)
void cvt7_f32_f16(CvtArgs a)
{
    const int bid = blockIdx.x;
    int t, lb;
    if      (bid < 2048) { t = 0; lb = bid; }
    else if (bid < 4096) { t = 1; lb = bid - 2048; }
    else if (bid < 6144) { t = 2; lb = bid - 4096; }
    else { const int r = bid - 6144; t = 3 + (r >> 7); lb = r & 127; }
    const float* __restrict__ src = a.s[t];
    _Float16*    __restrict__ dst = a.d[t];
    const int idx = lb * 2048 + threadIdx.x * 8;
    const float4 v0 = *(const float4*)&src[idx];
    const float4 v1 = *(const float4*)&src[idx + 4];
    half8v h;
    h[0] = (_Float16)v0.x; h[1] = (_Float16)v0.y; h[2] = (_Float16)v0.z; h[3] = (_Float16)v0.w;
    h[4] = (_Float16)v1.x; h[5] = (_Float16)v1.y; h[6] = (_Float16)v1.z; h[7] = (_Float16)v1.w;
    *(half8v*)&dst[idx] = h;
}

// ---------------------------------------------------------------------------
// fp16 MFMA GEMM body: C[128x128 tile] = A[M,512]h @ W[N,512]h^T.
// 4 waves, each owns a 64x64 quadrant (wr=w>>1, wc=w&1), acc 4x4 frags.
// LDS: A[128][32] + W[128][32] fp16, linear; staged via global_load_lds(16B).
// Per wave K-step: 4 gload_lds, 8 ds_read_b128, 16 MFMA (m97 ratio).
// ---------------------------------------------------------------------------
struct QkvPtrs {
    const _Float16* A[3];
    const _Float16* W[3];
    _Float16*       C[3];
};

#define GEMM_BODY(Ag, Wg)                                                      \
    __shared__ _Float16 Ash[128*32];                                           \
    __shared__ _Float16 Wsh[128*32];                                           \
    const int tid = threadIdx.x;                                               \
    const int w = tid >> 6, lane = tid & 63;                                   \
    const int lr = lane & 15, lg = lane >> 4;                                  \
    const int wr = w >> 1, wc = w & 1;                                         \
    const int col0 = blockIdx.x * 128;                                         \
    const int row0 = blockIdx.y * 128;                                         \
    f32x4 acc[4][4];                                                           \
    _Pragma("unroll")                                                          \
    for (int m = 0; m < 4; ++m)                                                \
        _Pragma("unroll")                                                      \
        for (int n = 0; n < 4; ++n) acc[m][n] = (f32x4)0.0f;                   \
    const int srow = lane >> 2;                                                \
    const int sg   = lane & 3;                                                 \
    for (int k0 = 0; k0 < 512; k0 += 32) {                                     \
        if (k0) __syncthreads();                                               \
        _Pragma("unroll")                                                      \
        for (int i = 0; i < 2; ++i) {                                          \
            const int j = w*2 + i;                                             \
            gload_lds16(&Ag[(size_t)(row0 + j*16 + srow)*512 + k0 + sg*8],     \
                        &Ash[j*512]);                                          \
            gload_lds16(&Wg[(size_t)(col0 + j*16 + srow)*512 + k0 + sg*8],     \
                        &Wsh[j*512]);                                          \
        }                                                                      \
        __syncthreads();                                                       \
        half8v af[4], bf[4];                                                   \
        _Pragma("unroll")                                                      \
        for (int m = 0; m < 4; ++m)                                            \
            af[m] = *(const half8v*)&Ash[(wr*64 + m*16 + lr)*32 + lg*8];       \
        _Pragma("unroll")                                                      \
        for (int n = 0; n < 4; ++n)                                            \
            bf[n] = *(const half8v*)&Wsh[(wc*64 + n*16 + lr)*32 + lg*8];       \
        _Pragma("unroll")                                                      \
        for (int m = 0; m < 4; ++m)                                            \
            _Pragma("unroll")                                                  \
            for (int n = 0; n < 4; ++n)                                        \
                acc[m][n] = __builtin_amdgcn_mfma_f32_16x16x32_f16(            \
                                af[m], bf[n], acc[m][n], 0, 0, 0);             \
    }

__global__ __launch_bounds__(256)
void gemm_qkv_f16(QkvPtrs p)
{
    const _Float16* Agp = p.A[blockIdx.z];
    const _Float16* Wgp = p.W[blockIdx.z];
    _Float16*       Cgp = p.C[blockIdx.z];
    GEMM_BODY(Agp, Wgp)
#pragma unroll
    for (int m = 0; m < 4; ++m)
#pragma unroll
    for (int n = 0; n < 4; ++n)
#pragma unroll
    for (int r = 0; r < 4; ++r) {
        const int row = row0 + wr*64 + m*16 + lg*4 + r;
        const int col = col0 + wc*64 + n*16 + lr;
        Cgp[(size_t)row*512 + col] = (_Float16)acc[m][n][r];
    }
}

__global__ __launch_bounds__(256)
void gemm_o_f16(const _Float16* __restrict__ Agp, const _Float16* __restrict__ Wgp,
                const float* __restrict__ bias, float* __restrict__ out)
{
    GEMM_BODY(Agp, Wgp)
#pragma unroll
    for (int m = 0; m < 4; ++m)
#pragma unroll
    for (int n = 0; n < 4; ++n)
#pragma unroll
    for (int r = 0; r < 4; ++r) {
        const int row = row0 + wr*64 + m*16 + lg*4 + r;
        const int col = col0 + wc*64 + n*16 + lr;
        out[(size_t)row*512 + col] = acc[m][n][r] + bias[col];
    }
}

// ---------------------------------------------------------------------------
// Flash attention, fp16 MFMA (fp32 accum, fp32 softmax). Same structure as
// round-4 bf16 version; operands fp16, no conversions in staging, scale
// 0.125 applied to fp32 scores post-MFMA. LDS 32 KB, swizzle: 16B-granule
// index ^= (row&7).
// ---------------------------------------------------------------------------
__global__ __launch_bounds__(256, 2)
void flash_attn_f16(const _Float16* __restrict__ Qp, const _Float16* __restrict__ Kp,
                    const _Float16* __restrict__ Vp, const uint8_t* __restrict__ mask,
                    _Float16* __restrict__ Op)
{
    __shared__ _Float16 KsL[64*64];     // 8 KB  [krow][dk] swizzled
    __shared__ _Float16 VtL[64*64];     // 8 KB  [dk][krow] swizzled
    __shared__ _Float16 PsL[4][32*64];  // 16 KB [qrow][k]  swizzled, per-wave

    const int tid  = threadIdx.x;
    const int w    = tid >> 6;
    const int lane = tid & 63;
    const int lr   = lane & 15;
    const int lg   = lane >> 4;
    const int q0   = blockIdx.x * 128;
    const int h    = blockIdx.y;
    const int b    = blockIdx.z;
    const size_t bS = (size_t)b * SS;

    // ---- Q fragments (raw; scale folded into score epilogue) ----
    half8v qf[2][2];
#pragma unroll
    for (int s2 = 0; s2 < 2; ++s2)
#pragma unroll
    for (int ds = 0; ds < 2; ++ds)
        qf[s2][ds] = *(const half8v*)&Qp[(bS + q0 + w*32 + s2*16 + lr) * DD + h*DKK + ds*32 + lg*8];

    float m_[2][4], l_[2][4];
    f32x4 Oc[2][4];
#pragma unroll
    for (int s2 = 0; s2 < 2; ++s2) {
#pragma unroll
        for (int r = 0; r < 4; ++r) { m_[s2][r] = -1e30f; l_[s2][r] = 0.0f; }
#pragma unroll
        for (int dt = 0; dt < 4; ++dt) Oc[s2][dt] = (f32x4)0.0f;
    }

    // staging geometry (fp16)
    const int krow = tid >> 2;          // K: row 0..63
    const int kg0  = (tid & 3) * 2;     //    two 16B granules kg0, kg0+1
    const int vr0  = (tid & 15) * 4;    // V: 4 rows vr0..vr0+3
    const int vc0  = (tid >> 4) * 4;    //    4 d-cols vc0..vc0+3

    half8v kpre[2];
    half4v vpre[4];
#pragma unroll
    for (int i = 0; i < 2; ++i)
        kpre[i] = *(const half8v*)&Kp[(bS + krow) * DD + h*DKK + (kg0 + i)*8];
#pragma unroll
    for (int j = 0; j < 4; ++j)
        vpre[j] = *(const half4v*)&Vp[(bS + vr0 + j) * DD + h*DKK + vc0];

    for (int it = 0; it < SS/64; ++it) {
        const int k0 = it * 64;
        __syncthreads();   // prior iteration's LDS reads complete

        // ---- stage K (row-major) and V (transposed), swizzled ----
#pragma unroll
        for (int i = 0; i < 2; ++i)
            *(half8v*)&KsL[krow*64 + (((kg0 + i) ^ (krow&7)) * 8)] = kpre[i];
#pragma unroll
        for (int j2 = 0; j2 < 4; ++j2) {
            const int d = vc0 + j2;
            half4v tv;
            tv[0] = vpre[0][j2]; tv[1] = vpre[1][j2];
            tv[2] = vpre[2][j2]; tv[3] = vpre[3][j2];
            *(half4v*)&VtL[d*64 + (((vr0>>3) ^ (d&7))*8 + (vr0&7))] = tv;
        }
        __syncthreads();   // staging visible

        // ---- prefetch next tile ----
        if (it + 1 < SS/64) {
            const int kn = k0 + 64;
#pragma unroll
            for (int i = 0; i < 2; ++i)
                kpre[i] = *(const half8v*)&Kp[(bS + kn + krow) * DD + h*DKK + (kg0 + i)*8];
#pragma unroll
            for (int j = 0; j < 4; ++j)
                vpre[j] = *(const half4v*)&Vp[(bS + kn + vr0 + j) * DD + h*DKK + vc0];
        }

        // ---- mask addends for this lane's 4 key columns ----
        float madd[4];
#pragma unroll
        for (int t = 0; t < 4; ++t)
            madd[t] = mask[bS + k0 + t*16 + lr] ? -INFINITY : 0.0f;

        // ---- K B-fragments ----
        half8v kfb[4][2];
#pragma unroll
        for (int t = 0; t < 4; ++t)
#pragma unroll
        for (int ds = 0; ds < 2; ++ds) {
            const int row = t*16 + lr;
            kfb[t][ds] = *(const half8v*)&KsL[row*64 + (((ds*4 + lg) ^ (row&7)) * 8)];
        }

        // ---- QK^T + online softmax per 16-row stripe ----
        float fac[2][4];
#pragma unroll
        for (int s2 = 0; s2 < 2; ++s2) {
            f32x4 sc[4];
#pragma unroll
            for (int t = 0; t < 4; ++t) {
                sc[t] = (f32x4)0.0f;
                sc[t] = __builtin_amdgcn_mfma_f32_16x16x32_f16(qf[s2][0], kfb[t][0], sc[t], 0, 0, 0);
                sc[t] = __builtin_amdgcn_mfma_f32_16x16x32_f16(qf[s2][1], kfb[t][1], sc[t], 0, 0, 0);
            }
            float ss[4][4];
#pragma unroll
            for (int t = 0; t < 4; ++t)
#pragma unroll
            for (int r = 0; r < 4; ++r) ss[t][r] = fmaf(sc[t][r], 0.125f, madd[t]);

#pragma unroll
            for (int r = 0; r < 4; ++r) {
                float tm = fmaxf(fmaxf(ss[0][r], ss[1][r]), fmaxf(ss[2][r], ss[3][r]));
#pragma unroll
                for (int off = 1; off <= 8; off <<= 1) tm = fmaxf(tm, __shfl_xor(tm, off));
                const float mn = fmaxf(m_[s2][r], tm);
                const float fc = __expf(m_[s2][r] - mn);
                m_[s2][r] = mn;
                float lsum = 0.0f;
#pragma unroll
                for (int t = 0; t < 4; ++t) {
                    const float p = __expf(ss[t][r] - mn);
                    ss[t][r] = p;
                    lsum += p;
                }
#pragma unroll
                for (int off = 1; off <= 8; off <<= 1) lsum += __shfl_xor(lsum, off);
                l_[s2][r] = l_[s2][r] * fc + lsum;
                fac[s2][r] = fc;
            }

            // ---- P -> per-wave LDS (fp16), granule swizzle ----
#pragma unroll
            for (int t = 0; t < 4; ++t)
#pragma unroll
            for (int r = 0; r < 4; ++r) {
                const int qrow = s2*16 + lg*4 + r;
                const int k = t*16 + lr;
                PsL[w][qrow*64 + (((k>>3) ^ (qrow&7))*8 + (k&7))] = (_Float16)ss[t][r];
            }
        }

        // ---- rescale O ----
#pragma unroll
        for (int s2 = 0; s2 < 2; ++s2)
#pragma unroll
        for (int dt = 0; dt < 4; ++dt)
#pragma unroll
        for (int r = 0; r < 4; ++r) Oc[s2][dt][r] *= fac[s2][r];

        // ---- PV ----
        half8v pf[2][2];
#pragma unroll
        for (int s2 = 0; s2 < 2; ++s2)
#pragma unroll
        for (int ks = 0; ks < 2; ++ks) {
            const int row = s2*16 + lr;
            pf[s2][ks] = *(const half8v*)&PsL[w][row*64 + (((ks*4 + lg) ^ (row&7)) * 8)];
        }
        half8v vfb[4][2];
#pragma unroll
        for (int dt = 0; dt < 4; ++dt)
#pragma unroll
        for (int ks = 0; ks < 2; ++ks) {
            const int d = dt*16 + lr;
            vfb[dt][ks] = *(const half8v*)&VtL[d*64 + (((ks*4 + lg) ^ (d&7)) * 8)];
        }
#pragma unroll
        for (int s2 = 0; s2 < 2; ++s2)
#pragma unroll
        for (int dt = 0; dt < 4; ++dt) {
            Oc[s2][dt] = __builtin_amdgcn_mfma_f32_16x16x32_f16(pf[s2][0], vfb[dt][0], Oc[s2][dt], 0, 0, 0);
            Oc[s2][dt] = __builtin_amdgcn_mfma_f32_16x16x32_f16(pf[s2][1], vfb[dt][1], Oc[s2][dt], 0, 0, 0);
        }
    }

    // ---- epilogue: normalize, store fp16 [b,s,h,dk] ----
#pragma unroll
    for (int s2 = 0; s2 < 2; ++s2)
#pragma unroll
    for (int r = 0; r < 4; ++r) {
        const float inv = (l_[s2][r] > 0.0f) ? (1.0f / l_[s2][r]) : 0.0f;
        const int q = q0 + w*32 + s2*16 + lg*4 + r;
#pragma unroll
        for (int dt = 0; dt < 4; ++dt)
            Op[(bS + q) * DD + h*DKK + dt*16 + lr] = (_Float16)(Oc[s2][dt][r] * inv);
    }
}

// ---------------------------------------------------------------------------
extern "C" void kernel_launch(void* const* d_in, const int* in_sizes, int n_in,
                              void* d_out, int out_size, void* d_ws, size_t ws_size,
                              hipStream_t stream)
{
    const float*   query = (const float*)d_in[0];
    const float*   key   = (const float*)d_in[1];
    const float*   value = (const float*)d_in[2];
    const uint8_t* mask  = (const uint8_t*)d_in[3];
    const float*   Wq    = (const float*)d_in[4];
    const float*   Wk    = (const float*)d_in[5];
    const float*   Wv    = (const float*)d_in[6];
    const float*   Wo    = (const float*)d_in[7];
    const float*   bo    = (const float*)d_in[8];
    float*         out   = (float*)d_out;

    _Float16* wsh = (_Float16*)d_ws;
    _Float16* qh  = wsh;                 // converted inputs
    _Float16* kh  = qh  + NE;
    _Float16* vh  = kh  + NE;
    _Float16* wqh = vh  + NE;            // converted weights
    _Float16* wkh = wqh + NW;
    _Float16* wvh = wkh + NW;
    _Float16* woh = wvh + NW;
    _Float16* Qh  = woh + NW;            // projected Q/K/V
    _Float16* Kh  = Qh  + NE;
    _Float16* Vh  = Kh  + NE;
    _Float16* Oh  = Vh  + NE;            // attention output

    CvtArgs ca;
    ca.s[0] = query; ca.s[1] = key; ca.s[2] = value;
    ca.s[3] = Wq; ca.s[4] = Wk; ca.s[5] = Wv; ca.s[6] = Wo;
    ca.d[0] = qh; ca.d[1] = kh; ca.d[2] = vh;
    ca.d[3] = wqh; ca.d[4] = wkh; ca.d[5] = wvh; ca.d[6] = woh;
    cvt7_f32_f16<<<6656, 256, 0, stream>>>(ca);

    QkvPtrs gp;
    gp.A[0] = qh;  gp.A[1] = kh;  gp.A[2] = vh;
    gp.W[0] = wqh; gp.W[1] = wkh; gp.W[2] = wvh;
    gp.C[0] = Qh;  gp.C[1] = Kh;  gp.C[2] = Vh;
    gemm_qkv_f16<<<dim3(DD/128, MR/128, 3), 256, 0, stream>>>(gp);

    flash_attn_f16<<<dim3(SS/128, HH, BB), 256, 0, stream>>>(Qh, Kh, Vh, mask, Oh);

    gemm_o_f16<<<dim3(DD/128, MR/128), 256, 0, stream>>>(Oh, woh, bo, out);
}